// Round 7
// baseline (493.943 us; speedup 1.0000x reference)
//
#include <hip/hip_runtime.h>
#include <math.h>

// N=50000, E=1600000, F_IN=128, C_OUT=64, HEADS=2, HC=128
#define NEG_SLOPE 0.2f
#define GN_EPS 1e-5f
#define NBSHIFT 8        // 256 nodes per coarse bucket
#define CHUNK 2048       // edges per partition block (R12)

typedef _Float16 h2 __attribute__((ext_vector_type(2)));
typedef _Float16 half8 __attribute__((ext_vector_type(8)));
typedef float f32x4 __attribute__((ext_vector_type(4)));

__device__ __forceinline__ int rfl(int v) {
  return __builtin_amdgcn_readfirstlane(v);
}

// ds_swizzle butterfly add: immediate BitMode pattern, NO per-lane addr VALU
// (vs __shfl_xor -> ds_bpermute + 2-3 VALU addr insts).
// xor1=0x041F xor2=0x081F xor4=0x101F xor16=0x401F (within 32-lane groups).
template <int PAT>
__device__ __forceinline__ float swz(float v) {
  return __builtin_bit_cast(
      float, (unsigned)__builtin_amdgcn_ds_swizzle(__builtin_bit_cast(int, v),
                                                   PAT));
}

// pack two f32 -> packed f16 dword (RTZ; ~5e-4 rel err)
__device__ __forceinline__ unsigned int pkh(float a, float b) {
  return __builtin_bit_cast(unsigned int, __builtin_amdgcn_cvt_pkrtz(a, b));
}

__device__ __forceinline__ h2 bch2(unsigned int u) {
  return __builtin_bit_cast(h2, u);
}

__device__ __forceinline__ h2 mkh2(float a, float b) {
  return __builtin_bit_cast(h2, __builtin_amdgcn_cvt_pkrtz(a, b));
}

__device__ __forceinline__ float dot2f(h2 a, h2 b, float c) {
#if __has_builtin(__builtin_amdgcn_fdot2)
  return __builtin_amdgcn_fdot2(a, b, c, false);
#else
  return fmaf((float)a.x, (float)b.x, fmaf((float)a.y, (float)b.y, c));
#endif
}

// logit contribution of one channel pair
__device__ __forceinline__ float lkdot(h2 xl, h2 xr, h2 a, float p) {
  h2 t = xl + xr;
  h2 z = {(_Float16)0.f, (_Float16)0.f};
#if __has_builtin(__builtin_elementwise_min)
  h2 mn = __builtin_elementwise_min(t, z);
#else
  h2 mn;
  mn.x = (t.x < z.x) ? t.x : z.x;
  mn.y = (t.y < z.y) ? t.y : z.y;
#endif
  h2 km1 = {(_Float16)(NEG_SLOPE - 1.0f), (_Float16)(NEG_SLOPE - 1.0f)};
  h2 g = mn * km1 + t;  // v_pk_fma_f16
  return dot2f(g, a, p);
}

// ---------------------------------------------------------------------------
// K1 (fused): MFMA gemm  +  coarse histogram (disjoint blockIdx ranges).
// ---------------------------------------------------------------------------
__global__ __launch_bounds__(256) void gemm_hist(
    const float* __restrict__ x, const float* __restrict__ Wl,
    const float* __restrict__ Wr, unsigned int* __restrict__ xlb,
    unsigned int* __restrict__ xrh, int n, const int* __restrict__ ei,
    int* __restrict__ bhist, int e, int gemm_blocks) {
  if ((int)blockIdx.x >= gemm_blocks) {
    __shared__ int hist[256];
    hist[threadIdx.x] = 0;
    __syncthreads();
    const int nbk = gridDim.x - gemm_blocks;
    const int stride = nbk * 256;
    for (int i = ((int)blockIdx.x - gemm_blocks) * 256 + threadIdx.x; i < e;
         i += stride)
      atomicAdd(&hist[ei[e + i] >> NBSHIFT], 1);
    __syncthreads();
    int v = hist[threadIdx.x];
    if (v > 0) atomicAdd(&bhist[threadIdx.x], v);
    return;
  }

  const int wv = threadIdx.x >> 6;  // wave 0..3
  const int lane = threadIdx.x & 63;
  const int lr = lane & 15;
  const int lk = lane >> 4;
  const int node0 = (int)blockIdx.x * 64;
  const float* __restrict__ Wp = (wv < 2) ? Wl : Wr;
  unsigned int* __restrict__ dst = (wv < 2) ? xlb : xrh;
  const int chBase = (wv & 1) * 64;

  f32x4 acc[4][4];
#pragma unroll
  for (int mt = 0; mt < 4; ++mt)
#pragma unroll
    for (int nt = 0; nt < 4; ++nt) acc[mt][nt] = (f32x4){0.f, 0.f, 0.f, 0.f};

  int nd[4];
#pragma unroll
  for (int nt = 0; nt < 4; ++nt) nd[nt] = min(node0 + nt * 16 + lr, n - 1);

#pragma unroll
  for (int kc = 0; kc < 4; ++kc) {
    const int k0 = kc * 32 + lk * 8;
    half8 a[4];
#pragma unroll
    for (int mt = 0; mt < 4; ++mt) {
      const float* __restrict__ wp =
          Wp + (size_t)k0 * 128 + chBase + mt * 16 + lr;
      float w0 = wp[0 * 128], w1 = wp[1 * 128], w2 = wp[2 * 128],
            w3 = wp[3 * 128];
      float w4 = wp[4 * 128], w5 = wp[5 * 128], w6 = wp[6 * 128],
            w7 = wp[7 * 128];
      uint4 ua;
      ua.x = pkh(w0, w1);
      ua.y = pkh(w2, w3);
      ua.z = pkh(w4, w5);
      ua.w = pkh(w6, w7);
      a[mt] = __builtin_bit_cast(half8, ua);
    }
    half8 b[4];
#pragma unroll
    for (int nt = 0; nt < 4; ++nt) {
      const float4 f0 = *(const float4*)(x + (size_t)nd[nt] * 128 + k0);
      const float4 f1 = *(const float4*)(x + (size_t)nd[nt] * 128 + k0 + 4);
      uint4 ub;
      ub.x = pkh(f0.x, f0.y);
      ub.y = pkh(f0.z, f0.w);
      ub.z = pkh(f1.x, f1.y);
      ub.w = pkh(f1.z, f1.w);
      b[nt] = __builtin_bit_cast(half8, ub);
    }
#pragma unroll
    for (int mt = 0; mt < 4; ++mt)
#pragma unroll
      for (int nt = 0; nt < 4; ++nt)
        acc[mt][nt] = __builtin_amdgcn_mfma_f32_16x16x32_f16(
            a[mt], b[nt], acc[mt][nt], 0, 0, 0);
  }

  const int dw0 = (chBase >> 1) + lk * 2;
#pragma unroll
  for (int nt = 0; nt < 4; ++nt) {
    const int node = node0 + nt * 16 + lr;
    if (node >= n) continue;
#pragma unroll
    for (int mt = 0; mt < 4; ++mt) {
      uint2 p;
      p.x = pkh(acc[mt][nt][0], acc[mt][nt][1]);
      p.y = pkh(acc[mt][nt][2], acc[mt][nt][3]);
      *(uint2*)(dst + (size_t)node * 64 + dw0 + mt * 8) = p;
    }
  }
}

// ---------------------------------------------------------------------------
// K3: exclusive scan of bucket counts -> bbase[nb+1], init gcur, sentinel
// ---------------------------------------------------------------------------
__global__ __launch_bounds__(256) void bscan(const int* __restrict__ bhist,
                                             int* __restrict__ bbase,
                                             int* __restrict__ gcur,
                                             int* __restrict__ offsets, int nb,
                                             int n, int e) {
  __shared__ int sd[256];
  int t = threadIdx.x;
  int v = (t < nb) ? bhist[t] : 0;
  sd[t] = v;
  __syncthreads();
#pragma unroll
  for (int s = 1; s < 256; s <<= 1) {
    int add = (t >= s) ? sd[t - s] : 0;
    __syncthreads();
    sd[t] += add;
    __syncthreads();
  }
  int excl = sd[t] - v;
  if (t < nb) {
    bbase[t] = excl;
    gcur[t] = excl;
  } else {
    gcur[t] = 0;
  }
  if (t == 0) {
    bbase[nb] = e;
    offsets[n] = e;
  }
}

// ---------------------------------------------------------------------------
// K4: partition (CHUNK=2048 -> 782 blocks for TLP).
// ---------------------------------------------------------------------------
__global__ __launch_bounds__(256) void partition(const int* __restrict__ ei,
                                                 int* __restrict__ gcur,
                                                 unsigned int* __restrict__ ebuf,
                                                 int e) {
  __shared__ int hist[256];
  __shared__ int lcur[256];
  const int t = threadIdx.x;
  const int c0 = blockIdx.x * CHUNK;
  const int cend = min(c0 + CHUNK, e);
  hist[t] = 0;
  __syncthreads();
  for (int i = c0 + t; i < cend; i += 256)
    atomicAdd(&hist[ei[e + i] >> NBSHIFT], 1);
  __syncthreads();
  lcur[t] = atomicAdd(&gcur[t], hist[t]);
  __syncthreads();
  for (int i = c0 + t; i < cend; i += 256) {
    int dst = ei[e + i];
    int src = ei[i];
    int b = dst >> NBSHIFT;
    int pos = atomicAdd(&lcur[b], 1);
    ebuf[pos] = (unsigned int)src | ((unsigned int)(dst & 255) << 16);
  }
}

// ---------------------------------------------------------------------------
// K5: per-bucket CSR build (1024 thr/block for latency hiding).
// ---------------------------------------------------------------------------
__global__ __launch_bounds__(1024) void csr_build(
    const unsigned int* __restrict__ ebuf, const int* __restrict__ bbase,
    int* __restrict__ offsets, int* __restrict__ csr_src, int n) {
  __shared__ int hist[256];
  __shared__ int sc[256];
  const int b = blockIdx.x;
  const int t = threadIdx.x;
  const int node0 = b << NBSHIFT;
  const int seg0 = bbase[b];
  const int seg1 = bbase[b + 1];

  if (t < 256) hist[t] = 0;
  __syncthreads();
  for (int i = seg0 + t; i < seg1; i += 1024)
    atomicAdd(&hist[(ebuf[i] >> 16) & 255], 1);
  __syncthreads();
  int v = 0;
  if (t < 256) {
    v = hist[t];
    sc[t] = v;
  }
  __syncthreads();
#pragma unroll
  for (int s = 1; s < 256; s <<= 1) {
    int add = (t >= s && t < 256) ? sc[t - s] : 0;
    __syncthreads();
    if (t < 256) sc[t] += add;
    __syncthreads();
  }
  if (t < 256) {
    int start = seg0 + sc[t] - v;
    int node = node0 + t;
    if (node < n) offsets[node] = start;
    hist[t] = start;
  }
  __syncthreads();
  for (int i = seg0 + t; i < seg1; i += 1024) {
    unsigned int u = ebuf[i];
    int pos = atomicAdd(&hist[(u >> 16) & 255], 1);
    csr_src[pos] = (int)(u & 0xFFFFu);
  }
}

// ---------------------------------------------------------------------------
// K6: per-node softmax attention + aggregation + FUSED GraphNorm partials.
// R13: (a) butterflies via ds_swizzle immediates (no bpermute addr VALU),
// (b) unroll 4 (4 gathers in flight), (c) each block accumulates its 4 output
// rows' per-channel S/Q in LDS and does ONE 256-float global atomicAdd --
// eliminates the gn_partial kernel (25.6MB re-read) entirely.
// No early return: all threads reach the barriers; inactive waves write 0.
// ---------------------------------------------------------------------------
__global__ __launch_bounds__(256) void node_agg(
    const unsigned int* __restrict__ xlh, const unsigned int* __restrict__ xrh,
    const int* __restrict__ offsets, const int* __restrict__ csr_src,
    const float* __restrict__ att, const float* __restrict__ bias,
    float* __restrict__ out, float* __restrict__ SQ, int n) {
  __shared__ float blkS[4][128];
  __shared__ float blkQ[4][128];
  const int wave = threadIdx.x >> 6;
  const int lane = threadIdx.x & 63;
  const int node = blockIdx.x * 4 + wave;
  const bool active = node < n;
  const int nc = active ? node : 0;
  const int q = lane >> 4;   // edge slot within quad
  const int r = lane & 15;   // channel group: ch 8r..8r+7 (head = r>>3)

  const uint4 xr4 = *(const uint4*)(xrh + (size_t)nc * 64 + r * 4);
  const h2 xr0 = bch2(xr4.x), xr1 = bch2(xr4.y), xr2v = bch2(xr4.z),
           xr3 = bch2(xr4.w);
  const float4 a0 = *(const float4*)(att + r * 8);
  const float4 a1 = *(const float4*)(att + r * 8 + 4);
  const h2 ah0 = mkh2(a0.x, a0.y), ah1 = mkh2(a0.z, a0.w),
           ah2 = mkh2(a1.x, a1.y), ah3 = mkh2(a1.z, a1.w);

  const int start = rfl(offsets[nc]);
  const int end = rfl(offsets[nc + 1]);
  const int deg = end - start;
  const int T = active ? deg + 1 : 0;  // +1 self-loop (slot 0)

  float s = 0.f;
  float accf[8];
#pragma unroll
  for (int i = 0; i < 8; ++i) accf[i] = 0.f;

  const char* __restrict__ xlbase = (const char*)xlh;
  const unsigned roff = (unsigned)(r * 16);

  auto quad = [&](int src, bool valid) {
    const uint4 xl4 =
        *(const uint4*)(xlbase + (((unsigned)src << 8) | roff));
    const h2 x0 = bch2(xl4.x), x1 = bch2(xl4.y), x2 = bch2(xl4.z),
             x3 = bch2(xl4.w);
    float p = 0.f;
    p = lkdot(x0, xr0, ah0, p);
    p = lkdot(x1, xr1, ah1, p);
    p = lkdot(x2, xr2v, ah2, p);
    p = lkdot(x3, xr3, ah3, p);
    // per-head reduce: 8 lanes per head within the 16-lane edge group
    p += swz<0x041F>(p);  // xor 1
    p += swz<0x081F>(p);  // xor 2
    p += swz<0x101F>(p);  // xor 4
    const float w = valid ? __expf(p) : 0.f;
    s += w;
    accf[0] = fmaf((float)x0.x, w, accf[0]);
    accf[1] = fmaf((float)x0.y, w, accf[1]);
    accf[2] = fmaf((float)x1.x, w, accf[2]);
    accf[3] = fmaf((float)x1.y, w, accf[3]);
    accf[4] = fmaf((float)x2.x, w, accf[4]);
    accf[5] = fmaf((float)x2.y, w, accf[5]);
    accf[6] = fmaf((float)x3.x, w, accf[6]);
    accf[7] = fmaf((float)x3.y, w, accf[7]);
  };

  for (int b0 = 0; b0 < T; b0 += 64) {
    const int m = min(64, T - b0);
    const int kk = b0 + lane;
    const int cl = min(kk, T - 1);
    int idx = nc;
    if (deg > 0) {
      idx = csr_src[start + max(cl - 1, 0)];
      if (cl == 0) idx = nc;
    }
    int j = 0;
#pragma unroll 4
    for (; j + 4 <= m; j += 4)
      quad(__shfl(idx, j + q, 64), true);
    if (j < m) {
      const int eo = j + q;
      quad(__shfl(idx, min(eo, m - 1), 64), eo < m);
    }
  }

  // cross-group (quad-slot) reduction: lanes 16 apart hold same channels/head
  s += swz<0x401F>(s);  // xor 16
  s += __shfl_xor(s, 32, 64);
#pragma unroll
  for (int i = 0; i < 8; ++i) {
    accf[i] += swz<0x401F>(accf[i]);
    accf[i] += __shfl_xor(accf[i], 32, 64);
  }

  if (q == 0) {
    float4 o0 = make_float4(0.f, 0.f, 0.f, 0.f);
    float4 o1 = make_float4(0.f, 0.f, 0.f, 0.f);
    if (active) {
      const float inv = 1.f / s;  // per-head denominator (lane's head)
      const float4 b0v = *(const float4*)(bias + r * 8);
      const float4 b1v = *(const float4*)(bias + r * 8 + 4);
      o0 = make_float4(fmaf(accf[0], inv, b0v.x), fmaf(accf[1], inv, b0v.y),
                       fmaf(accf[2], inv, b0v.z), fmaf(accf[3], inv, b0v.w));
      o1 = make_float4(fmaf(accf[4], inv, b1v.x), fmaf(accf[5], inv, b1v.y),
                       fmaf(accf[6], inv, b1v.z), fmaf(accf[7], inv, b1v.w));
      *(float4*)(out + (size_t)node * 128 + r * 8) = o0;
      *(float4*)(out + (size_t)node * 128 + r * 8 + 4) = o1;
    }
    *(float4*)&blkS[wave][r * 8] = o0;
    *(float4*)&blkS[wave][r * 8 + 4] = o1;
    float4 q0 = make_float4(o0.x * o0.x, o0.y * o0.y, o0.z * o0.z, o0.w * o0.w);
    float4 q1 = make_float4(o1.x * o1.x, o1.y * o1.y, o1.z * o1.z, o1.w * o1.w);
    *(float4*)&blkQ[wave][r * 8] = q0;
    *(float4*)&blkQ[wave][r * 8 + 4] = q1;
  }
  __syncthreads();
  // fold 4 waves' rows, one global atomic per channel-stat (t<128: S, else Q)
  const int t = threadIdx.x;
  float v;
  if (t < 128) {
    v = blkS[0][t] + blkS[1][t] + blkS[2][t] + blkS[3][t];
  } else {
    const int c = t - 128;
    v = blkQ[0][c] + blkQ[1][c] + blkQ[2][c] + blkQ[3][c];
  }
  atomicAdd(&SQ[t], v);
}

// K7b: finalize affine params from fused S/Q accumulators
__global__ void gn_final(const float* __restrict__ SQ,
                         const float* __restrict__ gw,
                         const float* __restrict__ gb,
                         const float* __restrict__ gms, float* __restrict__ AB,
                         float inv_n) {
  int c = threadIdx.x;  // 128 threads
  float S = SQ[c], Q = SQ[128 + c];
  float mean = S * inv_n;
  float msc = mean * gms[c];
  float var = Q * inv_n - 2.f * msc * mean + msc * msc;
  float scale = gw[c] * rsqrtf(var + GN_EPS);
  AB[c] = scale;
  AB[128 + c] = gb[c] - scale * msc;
}

// K7c: in-place normalize, float4-vectorized
__global__ void gn_apply(float* __restrict__ out, const float* __restrict__ AB,
                         int total4) {
  int i = blockIdx.x * blockDim.x + threadIdx.x;
  if (i >= total4) return;
  float4 v = ((float4*)out)[i];
  int c4 = (i & 31) * 4;
  v.x = fmaf(AB[c4 + 0], v.x, AB[128 + c4 + 0]);
  v.y = fmaf(AB[c4 + 1], v.y, AB[128 + c4 + 1]);
  v.z = fmaf(AB[c4 + 2], v.z, AB[128 + c4 + 2]);
  v.w = fmaf(AB[c4 + 3], v.w, AB[128 + c4 + 3]);
  ((float4*)out)[i] = v;
}

// ---------------------------------------------------------------------------
extern "C" void kernel_launch(void* const* d_in, const int* in_sizes, int n_in,
                              void* d_out, int out_size, void* d_ws,
                              size_t ws_size, hipStream_t stream) {
  const float* x = (const float*)d_in[0];
  const int* ei = (const int*)d_in[1];
  const float* Wl = (const float*)d_in[2];
  const float* Wr = (const float*)d_in[3];
  const float* att = (const float*)d_in[4];
  const float* bias = (const float*)d_in[5];
  const float* gw = (const float*)d_in[6];
  const float* gb = (const float*)d_in[7];
  const float* gms = (const float*)d_in[8];
  float* out = (float*)d_out;

  const int n = in_sizes[0] / 128;
  const int e = in_sizes[1] / 2;
  const int nb = (n + 255) >> NBSHIFT;       // coarse buckets (196)
  const int nchunks = (e + CHUNK - 1) / CHUNK;
  const int gemm_blocks = (n + 63) / 64;
  const int hist_blocks = 196;

  char* w = (char*)d_ws;
  auto alloc = [&](size_t bytes) {
    char* p = w;
    w += (bytes + 255) & ~(size_t)255;
    return p;
  };
  unsigned int* xlb = (unsigned int*)alloc((size_t)n * 64 * sizeof(int));
  unsigned int* xrh = (unsigned int*)alloc((size_t)n * 64 * sizeof(int));
  int* offsets = (int*)alloc((size_t)(n + 1) * sizeof(int));
  int* csr_src = (int*)alloc((size_t)e * sizeof(int));
  unsigned int* ebuf = (unsigned int*)alloc((size_t)e * sizeof(int));
  int* bhist = (int*)alloc(256 * sizeof(int));       // contiguous with SQ:
  float* SQ = (float*)alloc(256 * sizeof(float));    // one 2KB memset zeroes both
  int* bbase = (int*)alloc((size_t)(nb + 1) * sizeof(int));
  int* gcur = (int*)alloc(256 * sizeof(int));
  float* AB = (float*)alloc(256 * sizeof(float));

  hipMemsetAsync(bhist, 0, 2048, stream);  // bhist (1KB) + SQ (1KB)

  gemm_hist<<<gemm_blocks + hist_blocks, 256, 0, stream>>>(
      x, Wl, Wr, xlb, xrh, n, ei, bhist, e, gemm_blocks);
  bscan<<<1, 256, 0, stream>>>(bhist, bbase, gcur, offsets, nb, n, e);
  partition<<<nchunks, 256, 0, stream>>>(ei, gcur, ebuf, e);
  csr_build<<<nb, 1024, 0, stream>>>(ebuf, bbase, offsets, csr_src, n);
  node_agg<<<(n + 3) / 4, 256, 0, stream>>>(xlb, xrh, offsets, csr_src, att,
                                            bias, out, SQ, n);
  gn_final<<<1, 128, 0, stream>>>(SQ, gw, gb, gms, AB, 1.0f / (float)n);
  gn_apply<<<(n * 32 + 255) / 256, 256, 0, stream>>>(out, AB, n * 32);
}

// Round 8
// 247.694 us; speedup vs baseline: 1.9942x; 1.9942x over previous
//
#include <hip/hip_runtime.h>
#include <math.h>

// N=50000, E=1600000, F_IN=128, C_OUT=64, HEADS=2, HC=128
#define NEG_SLOPE 0.2f
#define GN_EPS 1e-5f
#define NBSHIFT 8        // 256 nodes per coarse bucket
#define CHUNK 2048       // edges per partition block (R12)

typedef _Float16 h2 __attribute__((ext_vector_type(2)));
typedef _Float16 half8 __attribute__((ext_vector_type(8)));
typedef float f32x4 __attribute__((ext_vector_type(4)));

__device__ __forceinline__ int rfl(int v) {
  return __builtin_amdgcn_readfirstlane(v);
}

// ds_swizzle butterfly add: immediate BitMode pattern, no per-lane addr VALU.
// xor1=0x041F xor2=0x081F xor4=0x101F xor16=0x401F (within 32-lane groups;
// xor16 never crosses the 32-lane boundary so it matches shfl_xor(.,16,64)).
template <int PAT>
__device__ __forceinline__ float swz(float v) {
  return __builtin_bit_cast(
      float, (unsigned)__builtin_amdgcn_ds_swizzle(__builtin_bit_cast(int, v),
                                                   PAT));
}

// pack two f32 -> packed f16 dword (RTZ; ~5e-4 rel err)
__device__ __forceinline__ unsigned int pkh(float a, float b) {
  return __builtin_bit_cast(unsigned int, __builtin_amdgcn_cvt_pkrtz(a, b));
}

__device__ __forceinline__ h2 bch2(unsigned int u) {
  return __builtin_bit_cast(h2, u);
}

__device__ __forceinline__ h2 mkh2(float a, float b) {
  return __builtin_bit_cast(h2, __builtin_amdgcn_cvt_pkrtz(a, b));
}

__device__ __forceinline__ float dot2f(h2 a, h2 b, float c) {
#if __has_builtin(__builtin_amdgcn_fdot2)
  return __builtin_amdgcn_fdot2(a, b, c, false);
#else
  return fmaf((float)a.x, (float)b.x, fmaf((float)a.y, (float)b.y, c));
#endif
}

// logit contribution of one channel pair
__device__ __forceinline__ float lkdot(h2 xl, h2 xr, h2 a, float p) {
  h2 t = xl + xr;
  h2 z = {(_Float16)0.f, (_Float16)0.f};
#if __has_builtin(__builtin_elementwise_min)
  h2 mn = __builtin_elementwise_min(t, z);
#else
  h2 mn;
  mn.x = (t.x < z.x) ? t.x : z.x;
  mn.y = (t.y < z.y) ? t.y : z.y;
#endif
  h2 km1 = {(_Float16)(NEG_SLOPE - 1.0f), (_Float16)(NEG_SLOPE - 1.0f)};
  h2 g = mn * km1 + t;  // v_pk_fma_f16
  return dot2f(g, a, p);
}

// ---------------------------------------------------------------------------
// K1 (fused): MFMA gemm  +  coarse histogram (disjoint blockIdx ranges).
// ---------------------------------------------------------------------------
__global__ __launch_bounds__(256) void gemm_hist(
    const float* __restrict__ x, const float* __restrict__ Wl,
    const float* __restrict__ Wr, unsigned int* __restrict__ xlb,
    unsigned int* __restrict__ xrh, int n, const int* __restrict__ ei,
    int* __restrict__ bhist, int e, int gemm_blocks) {
  if ((int)blockIdx.x >= gemm_blocks) {
    __shared__ int hist[256];
    hist[threadIdx.x] = 0;
    __syncthreads();
    const int nbk = gridDim.x - gemm_blocks;
    const int stride = nbk * 256;
    for (int i = ((int)blockIdx.x - gemm_blocks) * 256 + threadIdx.x; i < e;
         i += stride)
      atomicAdd(&hist[ei[e + i] >> NBSHIFT], 1);
    __syncthreads();
    int v = hist[threadIdx.x];
    if (v > 0) atomicAdd(&bhist[threadIdx.x], v);
    return;
  }

  const int wv = threadIdx.x >> 6;  // wave 0..3
  const int lane = threadIdx.x & 63;
  const int lr = lane & 15;
  const int lk = lane >> 4;
  const int node0 = (int)blockIdx.x * 64;
  const float* __restrict__ Wp = (wv < 2) ? Wl : Wr;
  unsigned int* __restrict__ dst = (wv < 2) ? xlb : xrh;
  const int chBase = (wv & 1) * 64;

  f32x4 acc[4][4];
#pragma unroll
  for (int mt = 0; mt < 4; ++mt)
#pragma unroll
    for (int nt = 0; nt < 4; ++nt) acc[mt][nt] = (f32x4){0.f, 0.f, 0.f, 0.f};

  int nd[4];
#pragma unroll
  for (int nt = 0; nt < 4; ++nt) nd[nt] = min(node0 + nt * 16 + lr, n - 1);

#pragma unroll
  for (int kc = 0; kc < 4; ++kc) {
    const int k0 = kc * 32 + lk * 8;
    half8 a[4];
#pragma unroll
    for (int mt = 0; mt < 4; ++mt) {
      const float* __restrict__ wp =
          Wp + (size_t)k0 * 128 + chBase + mt * 16 + lr;
      float w0 = wp[0 * 128], w1 = wp[1 * 128], w2 = wp[2 * 128],
            w3 = wp[3 * 128];
      float w4 = wp[4 * 128], w5 = wp[5 * 128], w6 = wp[6 * 128],
            w7 = wp[7 * 128];
      uint4 ua;
      ua.x = pkh(w0, w1);
      ua.y = pkh(w2, w3);
      ua.z = pkh(w4, w5);
      ua.w = pkh(w6, w7);
      a[mt] = __builtin_bit_cast(half8, ua);
    }
    half8 b[4];
#pragma unroll
    for (int nt = 0; nt < 4; ++nt) {
      const float4 f0 = *(const float4*)(x + (size_t)nd[nt] * 128 + k0);
      const float4 f1 = *(const float4*)(x + (size_t)nd[nt] * 128 + k0 + 4);
      uint4 ub;
      ub.x = pkh(f0.x, f0.y);
      ub.y = pkh(f0.z, f0.w);
      ub.z = pkh(f1.x, f1.y);
      ub.w = pkh(f1.z, f1.w);
      b[nt] = __builtin_bit_cast(half8, ub);
    }
#pragma unroll
    for (int mt = 0; mt < 4; ++mt)
#pragma unroll
      for (int nt = 0; nt < 4; ++nt)
        acc[mt][nt] = __builtin_amdgcn_mfma_f32_16x16x32_f16(
            a[mt], b[nt], acc[mt][nt], 0, 0, 0);
  }

  const int dw0 = (chBase >> 1) + lk * 2;
#pragma unroll
  for (int nt = 0; nt < 4; ++nt) {
    const int node = node0 + nt * 16 + lr;
    if (node >= n) continue;
#pragma unroll
    for (int mt = 0; mt < 4; ++mt) {
      uint2 p;
      p.x = pkh(acc[mt][nt][0], acc[mt][nt][1]);
      p.y = pkh(acc[mt][nt][2], acc[mt][nt][3]);
      *(uint2*)(dst + (size_t)node * 64 + dw0 + mt * 8) = p;
    }
  }
}

// ---------------------------------------------------------------------------
// K3: exclusive scan of bucket counts -> bbase[nb+1], init gcur, sentinel
// ---------------------------------------------------------------------------
__global__ __launch_bounds__(256) void bscan(const int* __restrict__ bhist,
                                             int* __restrict__ bbase,
                                             int* __restrict__ gcur,
                                             int* __restrict__ offsets, int nb,
                                             int n, int e) {
  __shared__ int sd[256];
  int t = threadIdx.x;
  int v = (t < nb) ? bhist[t] : 0;
  sd[t] = v;
  __syncthreads();
#pragma unroll
  for (int s = 1; s < 256; s <<= 1) {
    int add = (t >= s) ? sd[t - s] : 0;
    __syncthreads();
    sd[t] += add;
    __syncthreads();
  }
  int excl = sd[t] - v;
  if (t < nb) {
    bbase[t] = excl;
    gcur[t] = excl;
  } else {
    gcur[t] = 0;
  }
  if (t == 0) {
    bbase[nb] = e;
    offsets[n] = e;
  }
}

// ---------------------------------------------------------------------------
// K4: partition (CHUNK=2048 -> 782 blocks for TLP).
// ---------------------------------------------------------------------------
__global__ __launch_bounds__(256) void partition(const int* __restrict__ ei,
                                                 int* __restrict__ gcur,
                                                 unsigned int* __restrict__ ebuf,
                                                 int e) {
  __shared__ int hist[256];
  __shared__ int lcur[256];
  const int t = threadIdx.x;
  const int c0 = blockIdx.x * CHUNK;
  const int cend = min(c0 + CHUNK, e);
  hist[t] = 0;
  __syncthreads();
  for (int i = c0 + t; i < cend; i += 256)
    atomicAdd(&hist[ei[e + i] >> NBSHIFT], 1);
  __syncthreads();
  lcur[t] = atomicAdd(&gcur[t], hist[t]);
  __syncthreads();
  for (int i = c0 + t; i < cend; i += 256) {
    int dst = ei[e + i];
    int src = ei[i];
    int b = dst >> NBSHIFT;
    int pos = atomicAdd(&lcur[b], 1);
    ebuf[pos] = (unsigned int)src | ((unsigned int)(dst & 255) << 16);
  }
}

// ---------------------------------------------------------------------------
// K5: per-bucket CSR build (1024 thr/block for latency hiding).
// ---------------------------------------------------------------------------
__global__ __launch_bounds__(1024) void csr_build(
    const unsigned int* __restrict__ ebuf, const int* __restrict__ bbase,
    int* __restrict__ offsets, int* __restrict__ csr_src, int n) {
  __shared__ int hist[256];
  __shared__ int sc[256];
  const int b = blockIdx.x;
  const int t = threadIdx.x;
  const int node0 = b << NBSHIFT;
  const int seg0 = bbase[b];
  const int seg1 = bbase[b + 1];

  if (t < 256) hist[t] = 0;
  __syncthreads();
  for (int i = seg0 + t; i < seg1; i += 1024)
    atomicAdd(&hist[(ebuf[i] >> 16) & 255], 1);
  __syncthreads();
  int v = 0;
  if (t < 256) {
    v = hist[t];
    sc[t] = v;
  }
  __syncthreads();
#pragma unroll
  for (int s = 1; s < 256; s <<= 1) {
    int add = (t >= s && t < 256) ? sc[t - s] : 0;
    __syncthreads();
    if (t < 256) sc[t] += add;
    __syncthreads();
  }
  if (t < 256) {
    int start = seg0 + sc[t] - v;
    int node = node0 + t;
    if (node < n) offsets[node] = start;
    hist[t] = start;
  }
  __syncthreads();
  for (int i = seg0 + t; i < seg1; i += 1024) {
    unsigned int u = ebuf[i];
    int pos = atomicAdd(&hist[(u >> 16) & 255], 1);
    csr_src[pos] = (int)(u & 0xFFFFu);
  }
}

// ---------------------------------------------------------------------------
// K6: per-node softmax attention + aggregation.
// R14: reverted R13's fused-GN global atomics (3.2M adds into 1KB = XCD
// cacheline ping-pong, node_agg 62->312us). Kept: ds_swizzle butterflies,
// unroll 4 gather pipelining, SGPR-base+voffset gathers.
// ---------------------------------------------------------------------------
__global__ __launch_bounds__(256) void node_agg(
    const unsigned int* __restrict__ xlh, const unsigned int* __restrict__ xrh,
    const int* __restrict__ offsets, const int* __restrict__ csr_src,
    const float* __restrict__ att, const float* __restrict__ bias,
    float* __restrict__ out, int n) {
  const int wave = threadIdx.x >> 6;
  const int lane = threadIdx.x & 63;
  const int node = blockIdx.x * 4 + wave;
  if (node >= n) return;
  const int q = lane >> 4;   // edge slot within quad
  const int r = lane & 15;   // channel group: ch 8r..8r+7 (head = r>>3)

  const uint4 xr4 = *(const uint4*)(xrh + (size_t)node * 64 + r * 4);
  const h2 xr0 = bch2(xr4.x), xr1 = bch2(xr4.y), xr2v = bch2(xr4.z),
           xr3 = bch2(xr4.w);
  const float4 a0 = *(const float4*)(att + r * 8);
  const float4 a1 = *(const float4*)(att + r * 8 + 4);
  const h2 ah0 = mkh2(a0.x, a0.y), ah1 = mkh2(a0.z, a0.w),
           ah2 = mkh2(a1.x, a1.y), ah3 = mkh2(a1.z, a1.w);

  const int start = rfl(offsets[node]);
  const int end = rfl(offsets[node + 1]);
  const int deg = end - start;
  const int T = deg + 1;  // +1 self-loop (slot 0)

  float s = 0.f;
  float accf[8];
#pragma unroll
  for (int i = 0; i < 8; ++i) accf[i] = 0.f;

  const char* __restrict__ xlbase = (const char*)xlh;
  const unsigned roff = (unsigned)(r * 16);

  auto quad = [&](int src, bool valid) {
    const uint4 xl4 =
        *(const uint4*)(xlbase + (((unsigned)src << 8) | roff));
    const h2 x0 = bch2(xl4.x), x1 = bch2(xl4.y), x2 = bch2(xl4.z),
             x3 = bch2(xl4.w);
    float p = 0.f;
    p = lkdot(x0, xr0, ah0, p);
    p = lkdot(x1, xr1, ah1, p);
    p = lkdot(x2, xr2v, ah2, p);
    p = lkdot(x3, xr3, ah3, p);
    // per-head reduce: 8 lanes per head within the 16-lane edge group
    p += swz<0x041F>(p);  // xor 1
    p += swz<0x081F>(p);  // xor 2
    p += swz<0x101F>(p);  // xor 4
    const float w = valid ? __expf(p) : 0.f;
    s += w;
    accf[0] = fmaf((float)x0.x, w, accf[0]);
    accf[1] = fmaf((float)x0.y, w, accf[1]);
    accf[2] = fmaf((float)x1.x, w, accf[2]);
    accf[3] = fmaf((float)x1.y, w, accf[3]);
    accf[4] = fmaf((float)x2.x, w, accf[4]);
    accf[5] = fmaf((float)x2.y, w, accf[5]);
    accf[6] = fmaf((float)x3.x, w, accf[6]);
    accf[7] = fmaf((float)x3.y, w, accf[7]);
  };

  for (int b0 = 0; b0 < T; b0 += 64) {
    const int m = min(64, T - b0);
    const int kk = b0 + lane;
    const int cl = min(kk, T - 1);
    int idx = node;
    if (deg > 0) {
      idx = csr_src[start + max(cl - 1, 0)];
      if (cl == 0) idx = node;
    }
    int j = 0;
#pragma unroll 4
    for (; j + 4 <= m; j += 4)
      quad(__shfl(idx, j + q, 64), true);
    if (j < m) {
      const int eo = j + q;
      quad(__shfl(idx, min(eo, m - 1), 64), eo < m);
    }
  }

  // cross-group (quad-slot) reduction: lanes 16 apart hold same channels/head
  s += swz<0x401F>(s);  // xor 16
  s += __shfl_xor(s, 32, 64);
#pragma unroll
  for (int i = 0; i < 8; ++i) {
    accf[i] += swz<0x401F>(accf[i]);
    accf[i] += __shfl_xor(accf[i], 32, 64);
  }

  if (q == 0) {
    const float inv = 1.f / s;  // per-head denominator (lane's head)
    const float4 b0v = *(const float4*)(bias + r * 8);
    const float4 b1v = *(const float4*)(bias + r * 8 + 4);
    float4 o0 = make_float4(fmaf(accf[0], inv, b0v.x), fmaf(accf[1], inv, b0v.y),
                            fmaf(accf[2], inv, b0v.z), fmaf(accf[3], inv, b0v.w));
    float4 o1 = make_float4(fmaf(accf[4], inv, b1v.x), fmaf(accf[5], inv, b1v.y),
                            fmaf(accf[6], inv, b1v.z), fmaf(accf[7], inv, b1v.w));
    *(float4*)(out + (size_t)node * 128 + r * 8) = o0;
    *(float4*)(out + (size_t)node * 128 + r * 8 + 4) = o1;
  }
}

// ---------------------------------------------------------------------------
// K7a: per-channel sum & sumsq partials (float4 loads, 512 blocks).
// ---------------------------------------------------------------------------
__global__ __launch_bounds__(256) void gn_partial(const float4* __restrict__ out4,
                                                  float* __restrict__ part,
                                                  int total4) {
  const int t = threadIdx.x;
  float s0 = 0.f, s1 = 0.f, s2 = 0.f, s3 = 0.f;
  float q0 = 0.f, q1 = 0.f, q2 = 0.f, q3 = 0.f;
  const int stride = gridDim.x * 256;
  for (int i = blockIdx.x * 256 + t; i < total4; i += stride) {
    float4 v = out4[i];
    s0 += v.x; q0 = fmaf(v.x, v.x, q0);
    s1 += v.y; q1 = fmaf(v.y, v.y, q1);
    s2 += v.z; q2 = fmaf(v.z, v.z, q2);
    s3 += v.w; q3 = fmaf(v.w, v.w, q3);
  }
  __shared__ float red[8][128];
  const int row = t >> 5;
  const int cb = (t & 31) * 4;
  *(float4*)&red[row][cb] = make_float4(s0, s1, s2, s3);
  __syncthreads();
  if (t < 128) {
    float S = 0.f;
#pragma unroll
    for (int r = 0; r < 8; ++r) S += red[r][t];
    part[blockIdx.x * 256 + t] = S;
  }
  __syncthreads();
  *(float4*)&red[row][cb] = make_float4(q0, q1, q2, q3);
  __syncthreads();
  if (t < 128) {
    float Q = 0.f;
#pragma unroll
    for (int r = 0; r < 8; ++r) Q += red[r][t];
    part[blockIdx.x * 256 + 128 + t] = Q;
  }
}

// K7b: combine partials (1024 thr = 128 ch x 8 slices, LDS fold)
__global__ __launch_bounds__(1024) void gn_final(const float* __restrict__ part,
                                                 const float* __restrict__ gw,
                                                 const float* __restrict__ gb,
                                                 const float* __restrict__ gms,
                                                 float* __restrict__ AB,
                                                 int nblocks, float inv_n) {
  __shared__ float sS[8][128];
  __shared__ float sQ[8][128];
  const int c = threadIdx.x & 127;
  const int sl = threadIdx.x >> 7;  // 0..7
  float S = 0.f, Q = 0.f;
#pragma unroll 8
  for (int b = sl; b < nblocks; b += 8) {
    S += part[b * 256 + c];
    Q += part[b * 256 + 128 + c];
  }
  sS[sl][c] = S;
  sQ[sl][c] = Q;
  __syncthreads();
  if (sl == 0) {
#pragma unroll
    for (int i = 1; i < 8; ++i) {
      S += sS[i][c];
      Q += sQ[i][c];
    }
    float mean = S * inv_n;
    float msc = mean * gms[c];
    float var = Q * inv_n - 2.f * msc * mean + msc * msc;
    float scale = gw[c] * rsqrtf(var + GN_EPS);
    AB[c] = scale;
    AB[128 + c] = gb[c] - scale * msc;
  }
}

// K7c: in-place normalize, float4-vectorized
__global__ void gn_apply(float* __restrict__ out, const float* __restrict__ AB,
                         int total4) {
  int i = blockIdx.x * blockDim.x + threadIdx.x;
  if (i >= total4) return;
  float4 v = ((float4*)out)[i];
  int c4 = (i & 31) * 4;
  v.x = fmaf(AB[c4 + 0], v.x, AB[128 + c4 + 0]);
  v.y = fmaf(AB[c4 + 1], v.y, AB[128 + c4 + 1]);
  v.z = fmaf(AB[c4 + 2], v.z, AB[128 + c4 + 2]);
  v.w = fmaf(AB[c4 + 3], v.w, AB[128 + c4 + 3]);
  ((float4*)out)[i] = v;
}

// ---------------------------------------------------------------------------
extern "C" void kernel_launch(void* const* d_in, const int* in_sizes, int n_in,
                              void* d_out, int out_size, void* d_ws,
                              size_t ws_size, hipStream_t stream) {
  const float* x = (const float*)d_in[0];
  const int* ei = (const int*)d_in[1];
  const float* Wl = (const float*)d_in[2];
  const float* Wr = (const float*)d_in[3];
  const float* att = (const float*)d_in[4];
  const float* bias = (const float*)d_in[5];
  const float* gw = (const float*)d_in[6];
  const float* gb = (const float*)d_in[7];
  const float* gms = (const float*)d_in[8];
  float* out = (float*)d_out;

  const int n = in_sizes[0] / 128;
  const int e = in_sizes[1] / 2;
  const int nb = (n + 255) >> NBSHIFT;       // coarse buckets (196)
  const int nchunks = (e + CHUNK - 1) / CHUNK;
  const int GN_BLOCKS = 512;
  const int gemm_blocks = (n + 63) / 64;
  const int hist_blocks = 196;

  char* w = (char*)d_ws;
  auto alloc = [&](size_t bytes) {
    char* p = w;
    w += (bytes + 255) & ~(size_t)255;
    return p;
  };
  unsigned int* xlb = (unsigned int*)alloc((size_t)n * 64 * sizeof(int));
  unsigned int* xrh = (unsigned int*)alloc((size_t)n * 64 * sizeof(int));
  int* offsets = (int*)alloc((size_t)(n + 1) * sizeof(int));
  int* csr_src = (int*)alloc((size_t)e * sizeof(int));
  unsigned int* ebuf = (unsigned int*)alloc((size_t)e * sizeof(int));
  int* bhist = (int*)alloc(256 * sizeof(int));
  int* bbase = (int*)alloc((size_t)(nb + 1) * sizeof(int));
  int* gcur = (int*)alloc(256 * sizeof(int));
  float* part = (float*)alloc((size_t)GN_BLOCKS * 256 * sizeof(float));
  float* AB = (float*)alloc(256 * sizeof(float));

  hipMemsetAsync(bhist, 0, 256 * sizeof(int), stream);

  gemm_hist<<<gemm_blocks + hist_blocks, 256, 0, stream>>>(
      x, Wl, Wr, xlb, xrh, n, ei, bhist, e, gemm_blocks);
  bscan<<<1, 256, 0, stream>>>(bhist, bbase, gcur, offsets, nb, n, e);
  partition<<<nchunks, 256, 0, stream>>>(ei, gcur, ebuf, e);
  csr_build<<<nb, 1024, 0, stream>>>(ebuf, bbase, offsets, csr_src, n);
  node_agg<<<(n + 3) / 4, 256, 0, stream>>>(xlb, xrh, offsets, csr_src, att,
                                            bias, out, n);
  gn_partial<<<GN_BLOCKS, 256, 0, stream>>>((const float4*)out, part, n * 32);
  gn_final<<<1, 1024, 0, stream>>>(part, gw, gb, gms, AB, GN_BLOCKS,
                                   1.0f / (float)n);
  gn_apply<<<(n * 32 + 255) / 256, 256, 0, stream>>>(out, AB, n * 32);
}

// Round 9
// 241.059 us; speedup vs baseline: 2.0491x; 1.0275x over previous
//
#include <hip/hip_runtime.h>
#include <math.h>

// N=50000, E=1600000, F_IN=128, C_OUT=64, HEADS=2, HC=128
#define NEG_SLOPE 0.2f
#define GN_EPS 1e-5f
#define NBSHIFT 8        // 256 nodes per coarse bucket
#define CHUNK 2048       // edges per partition block (R12)

typedef _Float16 h2 __attribute__((ext_vector_type(2)));
typedef _Float16 half8 __attribute__((ext_vector_type(8)));
typedef float f32x4 __attribute__((ext_vector_type(4)));

__device__ __forceinline__ int rfl(int v) {
  return __builtin_amdgcn_readfirstlane(v);
}

// ds_swizzle butterfly add: immediate BitMode pattern, no per-lane addr VALU.
// xor1=0x041F xor2=0x081F xor4=0x101F xor16=0x401F (within 32-lane groups;
// xor16 never crosses the 32-lane boundary so it matches shfl_xor(.,16,64)).
template <int PAT>
__device__ __forceinline__ float swz(float v) {
  return __builtin_bit_cast(
      float, (unsigned)__builtin_amdgcn_ds_swizzle(__builtin_bit_cast(int, v),
                                                   PAT));
}

// pack two f32 -> packed f16 dword (RTZ; ~5e-4 rel err)
__device__ __forceinline__ unsigned int pkh(float a, float b) {
  return __builtin_bit_cast(unsigned int, __builtin_amdgcn_cvt_pkrtz(a, b));
}

__device__ __forceinline__ h2 bch2(unsigned int u) {
  return __builtin_bit_cast(h2, u);
}

__device__ __forceinline__ h2 mkh2(float a, float b) {
  return __builtin_bit_cast(h2, __builtin_amdgcn_cvt_pkrtz(a, b));
}

__device__ __forceinline__ float dot2f(h2 a, h2 b, float c) {
#if __has_builtin(__builtin_amdgcn_fdot2)
  return __builtin_amdgcn_fdot2(a, b, c, false);
#else
  return fmaf((float)a.x, (float)b.x, fmaf((float)a.y, (float)b.y, c));
#endif
}

// logit contribution of one channel pair
__device__ __forceinline__ float lkdot(h2 xl, h2 xr, h2 a, float p) {
  h2 t = xl + xr;
  h2 z = {(_Float16)0.f, (_Float16)0.f};
#if __has_builtin(__builtin_elementwise_min)
  h2 mn = __builtin_elementwise_min(t, z);
#else
  h2 mn;
  mn.x = (t.x < z.x) ? t.x : z.x;
  mn.y = (t.y < z.y) ? t.y : z.y;
#endif
  h2 km1 = {(_Float16)(NEG_SLOPE - 1.0f), (_Float16)(NEG_SLOPE - 1.0f)};
  h2 g = mn * km1 + t;  // v_pk_fma_f16
  return dot2f(g, a, p);
}

// ---------------------------------------------------------------------------
// K1 (fused): MFMA gemm  +  coarse histogram (disjoint blockIdx ranges).
// ---------------------------------------------------------------------------
__global__ __launch_bounds__(256) void gemm_hist(
    const float* __restrict__ x, const float* __restrict__ Wl,
    const float* __restrict__ Wr, unsigned int* __restrict__ xlb,
    unsigned int* __restrict__ xrh, int n, const int* __restrict__ ei,
    int* __restrict__ bhist, int e, int gemm_blocks) {
  if ((int)blockIdx.x >= gemm_blocks) {
    __shared__ int hist[256];
    hist[threadIdx.x] = 0;
    __syncthreads();
    const int nbk = gridDim.x - gemm_blocks;
    const int stride = nbk * 256;
    for (int i = ((int)blockIdx.x - gemm_blocks) * 256 + threadIdx.x; i < e;
         i += stride)
      atomicAdd(&hist[ei[e + i] >> NBSHIFT], 1);
    __syncthreads();
    int v = hist[threadIdx.x];
    if (v > 0) atomicAdd(&bhist[threadIdx.x], v);
    return;
  }

  const int wv = threadIdx.x >> 6;  // wave 0..3
  const int lane = threadIdx.x & 63;
  const int lr = lane & 15;
  const int lk = lane >> 4;
  const int node0 = (int)blockIdx.x * 64;
  const float* __restrict__ Wp = (wv < 2) ? Wl : Wr;
  unsigned int* __restrict__ dst = (wv < 2) ? xlb : xrh;
  const int chBase = (wv & 1) * 64;

  f32x4 acc[4][4];
#pragma unroll
  for (int mt = 0; mt < 4; ++mt)
#pragma unroll
    for (int nt = 0; nt < 4; ++nt) acc[mt][nt] = (f32x4){0.f, 0.f, 0.f, 0.f};

  int nd[4];
#pragma unroll
  for (int nt = 0; nt < 4; ++nt) nd[nt] = min(node0 + nt * 16 + lr, n - 1);

#pragma unroll
  for (int kc = 0; kc < 4; ++kc) {
    const int k0 = kc * 32 + lk * 8;
    half8 a[4];
#pragma unroll
    for (int mt = 0; mt < 4; ++mt) {
      const float* __restrict__ wp =
          Wp + (size_t)k0 * 128 + chBase + mt * 16 + lr;
      float w0 = wp[0 * 128], w1 = wp[1 * 128], w2 = wp[2 * 128],
            w3 = wp[3 * 128];
      float w4 = wp[4 * 128], w5 = wp[5 * 128], w6 = wp[6 * 128],
            w7 = wp[7 * 128];
      uint4 ua;
      ua.x = pkh(w0, w1);
      ua.y = pkh(w2, w3);
      ua.z = pkh(w4, w5);
      ua.w = pkh(w6, w7);
      a[mt] = __builtin_bit_cast(half8, ua);
    }
    half8 b[4];
#pragma unroll
    for (int nt = 0; nt < 4; ++nt) {
      const float4 f0 = *(const float4*)(x + (size_t)nd[nt] * 128 + k0);
      const float4 f1 = *(const float4*)(x + (size_t)nd[nt] * 128 + k0 + 4);
      uint4 ub;
      ub.x = pkh(f0.x, f0.y);
      ub.y = pkh(f0.z, f0.w);
      ub.z = pkh(f1.x, f1.y);
      ub.w = pkh(f1.z, f1.w);
      b[nt] = __builtin_bit_cast(half8, ub);
    }
#pragma unroll
    for (int mt = 0; mt < 4; ++mt)
#pragma unroll
      for (int nt = 0; nt < 4; ++nt)
        acc[mt][nt] = __builtin_amdgcn_mfma_f32_16x16x32_f16(
            a[mt], b[nt], acc[mt][nt], 0, 0, 0);
  }

  const int dw0 = (chBase >> 1) + lk * 2;
#pragma unroll
  for (int nt = 0; nt < 4; ++nt) {
    const int node = node0 + nt * 16 + lr;
    if (node >= n) continue;
#pragma unroll
    for (int mt = 0; mt < 4; ++mt) {
      uint2 p;
      p.x = pkh(acc[mt][nt][0], acc[mt][nt][1]);
      p.y = pkh(acc[mt][nt][2], acc[mt][nt][3]);
      *(uint2*)(dst + (size_t)node * 64 + dw0 + mt * 8) = p;
    }
  }
}

// ---------------------------------------------------------------------------
// K3: exclusive scan of bucket counts -> bbase[nb+1], init gcur, sentinel
// ---------------------------------------------------------------------------
__global__ __launch_bounds__(256) void bscan(const int* __restrict__ bhist,
                                             int* __restrict__ bbase,
                                             int* __restrict__ gcur,
                                             int* __restrict__ offsets, int nb,
                                             int n, int e) {
  __shared__ int sd[256];
  int t = threadIdx.x;
  int v = (t < nb) ? bhist[t] : 0;
  sd[t] = v;
  __syncthreads();
#pragma unroll
  for (int s = 1; s < 256; s <<= 1) {
    int add = (t >= s) ? sd[t - s] : 0;
    __syncthreads();
    sd[t] += add;
    __syncthreads();
  }
  int excl = sd[t] - v;
  if (t < nb) {
    bbase[t] = excl;
    gcur[t] = excl;
  } else {
    gcur[t] = 0;
  }
  if (t == 0) {
    bbase[nb] = e;
    offsets[n] = e;
  }
}

// ---------------------------------------------------------------------------
// K4: partition. R16: single global read pass — pass 1 reads src+dst once,
// builds entry src(16)|ldst(8)<<16|bucket(8)<<24 in LDS (8KB); pass 2 has
// ZERO global reads (was re-reading 12.8MB). csr_build masks fields, so the
// bucket byte rides along harmlessly into ebuf.
// ---------------------------------------------------------------------------
__global__ __launch_bounds__(256) void partition(const int* __restrict__ ei,
                                                 int* __restrict__ gcur,
                                                 unsigned int* __restrict__ ebuf,
                                                 int e) {
  __shared__ unsigned int ent[CHUNK];  // 8KB
  __shared__ int hist[256];
  __shared__ int lcur[256];
  const int t = threadIdx.x;
  const int c0 = blockIdx.x * CHUNK;
  const int cend = min(c0 + CHUNK, e);
  hist[t] = 0;
  __syncthreads();
  for (int i = c0 + t; i < cend; i += 256) {
    const int dst = ei[e + i];
    const int src = ei[i];
    const int b = dst >> NBSHIFT;
    atomicAdd(&hist[b], 1);
    ent[i - c0] = (unsigned int)src | ((unsigned int)(dst & 255) << 16) |
                  ((unsigned int)b << 24);
  }
  __syncthreads();
  lcur[t] = atomicAdd(&gcur[t], hist[t]);
  __syncthreads();
  for (int i = c0 + t; i < cend; i += 256) {
    const unsigned int u = ent[i - c0];
    const int b = u >> 24;
    int pos = atomicAdd(&lcur[b], 1);
    ebuf[pos] = u;
  }
}

// ---------------------------------------------------------------------------
// K5: per-bucket CSR build (1024 thr/block). R16: csr_src is uint16
// (N<65536) — halves the scattered write traffic and node_agg's index reads.
// ---------------------------------------------------------------------------
__global__ __launch_bounds__(1024) void csr_build(
    const unsigned int* __restrict__ ebuf, const int* __restrict__ bbase,
    int* __restrict__ offsets, unsigned short* __restrict__ csr16, int n) {
  __shared__ int hist[256];
  __shared__ int sc[256];
  const int b = blockIdx.x;
  const int t = threadIdx.x;
  const int node0 = b << NBSHIFT;
  const int seg0 = bbase[b];
  const int seg1 = bbase[b + 1];

  if (t < 256) hist[t] = 0;
  __syncthreads();
  for (int i = seg0 + t; i < seg1; i += 1024)
    atomicAdd(&hist[(ebuf[i] >> 16) & 255], 1);
  __syncthreads();
  int v = 0;
  if (t < 256) {
    v = hist[t];
    sc[t] = v;
  }
  __syncthreads();
#pragma unroll
  for (int s = 1; s < 256; s <<= 1) {
    int add = (t >= s && t < 256) ? sc[t - s] : 0;
    __syncthreads();
    if (t < 256) sc[t] += add;
    __syncthreads();
  }
  if (t < 256) {
    int start = seg0 + sc[t] - v;
    int node = node0 + t;
    if (node < n) offsets[node] = start;
    hist[t] = start;
  }
  __syncthreads();
  for (int i = seg0 + t; i < seg1; i += 1024) {
    unsigned int u = ebuf[i];
    int pos = atomicAdd(&hist[(u >> 16) & 255], 1);
    csr16[pos] = (unsigned short)(u & 0xFFFFu);
  }
}

// ---------------------------------------------------------------------------
// K6: per-node softmax attention + aggregation.
// 16 lanes/edge, 4 edges/wave-iter; ds_swizzle butterflies; unroll 4;
// SGPR-base+voffset gathers. R16: index stream is uint16.
// ---------------------------------------------------------------------------
__global__ __launch_bounds__(256) void node_agg(
    const unsigned int* __restrict__ xlh, const unsigned int* __restrict__ xrh,
    const int* __restrict__ offsets, const unsigned short* __restrict__ csr16,
    const float* __restrict__ att, const float* __restrict__ bias,
    float* __restrict__ out, int n) {
  const int wave = threadIdx.x >> 6;
  const int lane = threadIdx.x & 63;
  const int node = blockIdx.x * 4 + wave;
  if (node >= n) return;
  const int q = lane >> 4;   // edge slot within quad
  const int r = lane & 15;   // channel group: ch 8r..8r+7 (head = r>>3)

  const uint4 xr4 = *(const uint4*)(xrh + (size_t)node * 64 + r * 4);
  const h2 xr0 = bch2(xr4.x), xr1 = bch2(xr4.y), xr2v = bch2(xr4.z),
           xr3 = bch2(xr4.w);
  const float4 a0 = *(const float4*)(att + r * 8);
  const float4 a1 = *(const float4*)(att + r * 8 + 4);
  const h2 ah0 = mkh2(a0.x, a0.y), ah1 = mkh2(a0.z, a0.w),
           ah2 = mkh2(a1.x, a1.y), ah3 = mkh2(a1.z, a1.w);

  const int start = rfl(offsets[node]);
  const int end = rfl(offsets[node + 1]);
  const int deg = end - start;
  const int T = deg + 1;  // +1 self-loop (slot 0)

  float s = 0.f;
  float accf[8];
#pragma unroll
  for (int i = 0; i < 8; ++i) accf[i] = 0.f;

  const char* __restrict__ xlbase = (const char*)xlh;
  const unsigned roff = (unsigned)(r * 16);

  auto quad = [&](int src, bool valid) {
    const uint4 xl4 =
        *(const uint4*)(xlbase + (((unsigned)src << 8) | roff));
    const h2 x0 = bch2(xl4.x), x1 = bch2(xl4.y), x2 = bch2(xl4.z),
             x3 = bch2(xl4.w);
    float p = 0.f;
    p = lkdot(x0, xr0, ah0, p);
    p = lkdot(x1, xr1, ah1, p);
    p = lkdot(x2, xr2v, ah2, p);
    p = lkdot(x3, xr3, ah3, p);
    // per-head reduce: 8 lanes per head within the 16-lane edge group
    p += swz<0x041F>(p);  // xor 1
    p += swz<0x081F>(p);  // xor 2
    p += swz<0x101F>(p);  // xor 4
    const float w = valid ? __expf(p) : 0.f;
    s += w;
    accf[0] = fmaf((float)x0.x, w, accf[0]);
    accf[1] = fmaf((float)x0.y, w, accf[1]);
    accf[2] = fmaf((float)x1.x, w, accf[2]);
    accf[3] = fmaf((float)x1.y, w, accf[3]);
    accf[4] = fmaf((float)x2.x, w, accf[4]);
    accf[5] = fmaf((float)x2.y, w, accf[5]);
    accf[6] = fmaf((float)x3.x, w, accf[6]);
    accf[7] = fmaf((float)x3.y, w, accf[7]);
  };

  for (int b0 = 0; b0 < T; b0 += 64) {
    const int m = min(64, T - b0);
    const int kk = b0 + lane;
    const int cl = min(kk, T - 1);
    int idx = node;
    if (deg > 0) {
      idx = csr16[start + max(cl - 1, 0)];
      if (cl == 0) idx = node;
    }
    int j = 0;
#pragma unroll 4
    for (; j + 4 <= m; j += 4)
      quad(__shfl(idx, j + q, 64), true);
    if (j < m) {
      const int eo = j + q;
      quad(__shfl(idx, min(eo, m - 1), 64), eo < m);
    }
  }

  // cross-group (quad-slot) reduction: lanes 16 apart hold same channels/head
  s += swz<0x401F>(s);  // xor 16
  s += __shfl_xor(s, 32, 64);
#pragma unroll
  for (int i = 0; i < 8; ++i) {
    accf[i] += swz<0x401F>(accf[i]);
    accf[i] += __shfl_xor(accf[i], 32, 64);
  }

  if (q == 0) {
    const float inv = 1.f / s;  // per-head denominator (lane's head)
    const float4 b0v = *(const float4*)(bias + r * 8);
    const float4 b1v = *(const float4*)(bias + r * 8 + 4);
    float4 o0 = make_float4(fmaf(accf[0], inv, b0v.x), fmaf(accf[1], inv, b0v.y),
                            fmaf(accf[2], inv, b0v.z), fmaf(accf[3], inv, b0v.w));
    float4 o1 = make_float4(fmaf(accf[4], inv, b1v.x), fmaf(accf[5], inv, b1v.y),
                            fmaf(accf[6], inv, b1v.z), fmaf(accf[7], inv, b1v.w));
    *(float4*)(out + (size_t)node * 128 + r * 8) = o0;
    *(float4*)(out + (size_t)node * 128 + r * 8 + 4) = o1;
  }
}

// ---------------------------------------------------------------------------
// K7a: per-channel sum & sumsq partials (float4 loads, 512 blocks).
// ---------------------------------------------------------------------------
__global__ __launch_bounds__(256) void gn_partial(const float4* __restrict__ out4,
                                                  float* __restrict__ part,
                                                  int total4) {
  const int t = threadIdx.x;
  float s0 = 0.f, s1 = 0.f, s2 = 0.f, s3 = 0.f;
  float q0 = 0.f, q1 = 0.f, q2 = 0.f, q3 = 0.f;
  const int stride = gridDim.x * 256;
  for (int i = blockIdx.x * 256 + t; i < total4; i += stride) {
    float4 v = out4[i];
    s0 += v.x; q0 = fmaf(v.x, v.x, q0);
    s1 += v.y; q1 = fmaf(v.y, v.y, q1);
    s2 += v.z; q2 = fmaf(v.z, v.z, q2);
    s3 += v.w; q3 = fmaf(v.w, v.w, q3);
  }
  __shared__ float red[8][128];
  const int row = t >> 5;
  const int cb = (t & 31) * 4;
  *(float4*)&red[row][cb] = make_float4(s0, s1, s2, s3);
  __syncthreads();
  if (t < 128) {
    float S = 0.f;
#pragma unroll
    for (int r = 0; r < 8; ++r) S += red[r][t];
    part[blockIdx.x * 256 + t] = S;
  }
  __syncthreads();
  *(float4*)&red[row][cb] = make_float4(q0, q1, q2, q3);
  __syncthreads();
  if (t < 128) {
    float Q = 0.f;
#pragma unroll
    for (int r = 0; r < 8; ++r) Q += red[r][t];
    part[blockIdx.x * 256 + 128 + t] = Q;
  }
}

// K7b: combine partials (1024 thr = 128 ch x 8 slices, LDS fold)
__global__ __launch_bounds__(1024) void gn_final(const float* __restrict__ part,
                                                 const float* __restrict__ gw,
                                                 const float* __restrict__ gb,
                                                 const float* __restrict__ gms,
                                                 float* __restrict__ AB,
                                                 int nblocks, float inv_n) {
  __shared__ float sS[8][128];
  __shared__ float sQ[8][128];
  const int c = threadIdx.x & 127;
  const int sl = threadIdx.x >> 7;  // 0..7
  float S = 0.f, Q = 0.f;
#pragma unroll 8
  for (int b = sl; b < nblocks; b += 8) {
    S += part[b * 256 + c];
    Q += part[b * 256 + 128 + c];
  }
  sS[sl][c] = S;
  sQ[sl][c] = Q;
  __syncthreads();
  if (sl == 0) {
#pragma unroll
    for (int i = 1; i < 8; ++i) {
      S += sS[i][c];
      Q += sQ[i][c];
    }
    float mean = S * inv_n;
    float msc = mean * gms[c];
    float var = Q * inv_n - 2.f * msc * mean + msc * msc;
    float scale = gw[c] * rsqrtf(var + GN_EPS);
    AB[c] = scale;
    AB[128 + c] = gb[c] - scale * msc;
  }
}

// K7c: in-place normalize, float4-vectorized
__global__ void gn_apply(float* __restrict__ out, const float* __restrict__ AB,
                         int total4) {
  int i = blockIdx.x * blockDim.x + threadIdx.x;
  if (i >= total4) return;
  float4 v = ((float4*)out)[i];
  int c4 = (i & 31) * 4;
  v.x = fmaf(AB[c4 + 0], v.x, AB[128 + c4 + 0]);
  v.y = fmaf(AB[c4 + 1], v.y, AB[128 + c4 + 1]);
  v.z = fmaf(AB[c4 + 2], v.z, AB[128 + c4 + 2]);
  v.w = fmaf(AB[c4 + 3], v.w, AB[128 + c4 + 3]);
  ((float4*)out)[i] = v;
}

// ---------------------------------------------------------------------------
extern "C" void kernel_launch(void* const* d_in, const int* in_sizes, int n_in,
                              void* d_out, int out_size, void* d_ws,
                              size_t ws_size, hipStream_t stream) {
  const float* x = (const float*)d_in[0];
  const int* ei = (const int*)d_in[1];
  const float* Wl = (const float*)d_in[2];
  const float* Wr = (const float*)d_in[3];
  const float* att = (const float*)d_in[4];
  const float* bias = (const float*)d_in[5];
  const float* gw = (const float*)d_in[6];
  const float* gb = (const float*)d_in[7];
  const float* gms = (const float*)d_in[8];
  float* out = (float*)d_out;

  const int n = in_sizes[0] / 128;
  const int e = in_sizes[1] / 2;
  const int nb = (n + 255) >> NBSHIFT;       // coarse buckets (196)
  const int nchunks = (e + CHUNK - 1) / CHUNK;
  const int GN_BLOCKS = 512;
  const int gemm_blocks = (n + 63) / 64;
  const int hist_blocks = 196;

  char* w = (char*)d_ws;
  auto alloc = [&](size_t bytes) {
    char* p = w;
    w += (bytes + 255) & ~(size_t)255;
    return p;
  };
  unsigned int* xlb = (unsigned int*)alloc((size_t)n * 64 * sizeof(int));
  unsigned int* xrh = (unsigned int*)alloc((size_t)n * 64 * sizeof(int));
  int* offsets = (int*)alloc((size_t)(n + 1) * sizeof(int));
  unsigned short* csr16 =
      (unsigned short*)alloc((size_t)e * sizeof(unsigned short));
  unsigned int* ebuf = (unsigned int*)alloc((size_t)e * sizeof(int));
  int* bhist = (int*)alloc(256 * sizeof(int));
  int* bbase = (int*)alloc((size_t)(nb + 1) * sizeof(int));
  int* gcur = (int*)alloc(256 * sizeof(int));
  float* part = (float*)alloc((size_t)GN_BLOCKS * 256 * sizeof(float));
  float* AB = (float*)alloc(256 * sizeof(float));

  hipMemsetAsync(bhist, 0, 256 * sizeof(int), stream);

  gemm_hist<<<gemm_blocks + hist_blocks, 256, 0, stream>>>(
      x, Wl, Wr, xlb, xrh, n, ei, bhist, e, gemm_blocks);
  bscan<<<1, 256, 0, stream>>>(bhist, bbase, gcur, offsets, nb, n, e);
  partition<<<nchunks, 256, 0, stream>>>(ei, gcur, ebuf, e);
  csr_build<<<nb, 1024, 0, stream>>>(ebuf, bbase, offsets, csr16, n);
  node_agg<<<(n + 3) / 4, 256, 0, stream>>>(xlb, xrh, offsets, csr16, att,
                                            bias, out, n);
  gn_partial<<<GN_BLOCKS, 256, 0, stream>>>((const float4*)out, part, n * 32);
  gn_final<<<1, 1024, 0, stream>>>(part, gw, gb, gms, AB, GN_BLOCKS,
                                   1.0f / (float)n);
  gn_apply<<<(n * 32 + 255) / 256, 256, 0, stream>>>(out, AB, n * 32);
}

// Round 10
// 236.609 us; speedup vs baseline: 2.0876x; 1.0188x over previous
//
#include <hip/hip_runtime.h>
#include <math.h>

// N=50000, E=1600000, F_IN=128, C_OUT=64, HEADS=2, HC=128
#define NEG_SLOPE 0.2f
#define GN_EPS 1e-5f
#define NBSHIFT 8        // 256 nodes per coarse bucket
#define CHUNK 2048       // edges per partition block (R12)

typedef _Float16 h2 __attribute__((ext_vector_type(2)));
typedef _Float16 half8 __attribute__((ext_vector_type(8)));
typedef float f32x4 __attribute__((ext_vector_type(4)));

__device__ __forceinline__ int rfl(int v) {
  return __builtin_amdgcn_readfirstlane(v);
}

// ds_swizzle butterfly add: immediate BitMode pattern, no per-lane addr VALU.
// xor1=0x041F xor2=0x081F xor4=0x101F xor16=0x401F (within 32-lane groups;
// xor16 never crosses the 32-lane boundary so it matches shfl_xor(.,16,64)).
template <int PAT>
__device__ __forceinline__ float swz(float v) {
  return __builtin_bit_cast(
      float, (unsigned)__builtin_amdgcn_ds_swizzle(__builtin_bit_cast(int, v),
                                                   PAT));
}

// pack two f32 -> packed f16 dword (RTZ; ~5e-4 rel err)
__device__ __forceinline__ unsigned int pkh(float a, float b) {
  return __builtin_bit_cast(unsigned int, __builtin_amdgcn_cvt_pkrtz(a, b));
}

__device__ __forceinline__ h2 bch2(unsigned int u) {
  return __builtin_bit_cast(h2, u);
}

__device__ __forceinline__ h2 mkh2(float a, float b) {
  return __builtin_bit_cast(h2, __builtin_amdgcn_cvt_pkrtz(a, b));
}

__device__ __forceinline__ float dot2f(h2 a, h2 b, float c) {
#if __has_builtin(__builtin_amdgcn_fdot2)
  return __builtin_amdgcn_fdot2(a, b, c, false);
#else
  return fmaf((float)a.x, (float)b.x, fmaf((float)a.y, (float)b.y, c));
#endif
}

// logit contribution of one channel pair
__device__ __forceinline__ float lkdot(h2 xl, h2 xr, h2 a, float p) {
  h2 t = xl + xr;
  h2 z = {(_Float16)0.f, (_Float16)0.f};
#if __has_builtin(__builtin_elementwise_min)
  h2 mn = __builtin_elementwise_min(t, z);
#else
  h2 mn;
  mn.x = (t.x < z.x) ? t.x : z.x;
  mn.y = (t.y < z.y) ? t.y : z.y;
#endif
  h2 km1 = {(_Float16)(NEG_SLOPE - 1.0f), (_Float16)(NEG_SLOPE - 1.0f)};
  h2 g = mn * km1 + t;  // v_pk_fma_f16
  return dot2f(g, a, p);
}

// ---------------------------------------------------------------------------
// K1 (fused): MFMA gemm  +  coarse histogram (disjoint blockIdx ranges).
// ---------------------------------------------------------------------------
__global__ __launch_bounds__(256) void gemm_hist(
    const float* __restrict__ x, const float* __restrict__ Wl,
    const float* __restrict__ Wr, unsigned int* __restrict__ xlb,
    unsigned int* __restrict__ xrh, int n, const int* __restrict__ ei,
    int* __restrict__ bhist, int e, int gemm_blocks) {
  if ((int)blockIdx.x >= gemm_blocks) {
    __shared__ int hist[256];
    hist[threadIdx.x] = 0;
    __syncthreads();
    const int nbk = gridDim.x - gemm_blocks;
    const int stride = nbk * 256;
    for (int i = ((int)blockIdx.x - gemm_blocks) * 256 + threadIdx.x; i < e;
         i += stride)
      atomicAdd(&hist[ei[e + i] >> NBSHIFT], 1);
    __syncthreads();
    int v = hist[threadIdx.x];
    if (v > 0) atomicAdd(&bhist[threadIdx.x], v);
    return;
  }

  const int wv = threadIdx.x >> 6;  // wave 0..3
  const int lane = threadIdx.x & 63;
  const int lr = lane & 15;
  const int lk = lane >> 4;
  const int node0 = (int)blockIdx.x * 64;
  const float* __restrict__ Wp = (wv < 2) ? Wl : Wr;
  unsigned int* __restrict__ dst = (wv < 2) ? xlb : xrh;
  const int chBase = (wv & 1) * 64;

  f32x4 acc[4][4];
#pragma unroll
  for (int mt = 0; mt < 4; ++mt)
#pragma unroll
    for (int nt = 0; nt < 4; ++nt) acc[mt][nt] = (f32x4){0.f, 0.f, 0.f, 0.f};

  int nd[4];
#pragma unroll
  for (int nt = 0; nt < 4; ++nt) nd[nt] = min(node0 + nt * 16 + lr, n - 1);

#pragma unroll
  for (int kc = 0; kc < 4; ++kc) {
    const int k0 = kc * 32 + lk * 8;
    half8 a[4];
#pragma unroll
    for (int mt = 0; mt < 4; ++mt) {
      const float* __restrict__ wp =
          Wp + (size_t)k0 * 128 + chBase + mt * 16 + lr;
      float w0 = wp[0 * 128], w1 = wp[1 * 128], w2 = wp[2 * 128],
            w3 = wp[3 * 128];
      float w4 = wp[4 * 128], w5 = wp[5 * 128], w6 = wp[6 * 128],
            w7 = wp[7 * 128];
      uint4 ua;
      ua.x = pkh(w0, w1);
      ua.y = pkh(w2, w3);
      ua.z = pkh(w4, w5);
      ua.w = pkh(w6, w7);
      a[mt] = __builtin_bit_cast(half8, ua);
    }
    half8 b[4];
#pragma unroll
    for (int nt = 0; nt < 4; ++nt) {
      const float4 f0 = *(const float4*)(x + (size_t)nd[nt] * 128 + k0);
      const float4 f1 = *(const float4*)(x + (size_t)nd[nt] * 128 + k0 + 4);
      uint4 ub;
      ub.x = pkh(f0.x, f0.y);
      ub.y = pkh(f0.z, f0.w);
      ub.z = pkh(f1.x, f1.y);
      ub.w = pkh(f1.z, f1.w);
      b[nt] = __builtin_bit_cast(half8, ub);
    }
#pragma unroll
    for (int mt = 0; mt < 4; ++mt)
#pragma unroll
      for (int nt = 0; nt < 4; ++nt)
        acc[mt][nt] = __builtin_amdgcn_mfma_f32_16x16x32_f16(
            a[mt], b[nt], acc[mt][nt], 0, 0, 0);
  }

  const int dw0 = (chBase >> 1) + lk * 2;
#pragma unroll
  for (int nt = 0; nt < 4; ++nt) {
    const int node = node0 + nt * 16 + lr;
    if (node >= n) continue;
#pragma unroll
    for (int mt = 0; mt < 4; ++mt) {
      uint2 p;
      p.x = pkh(acc[mt][nt][0], acc[mt][nt][1]);
      p.y = pkh(acc[mt][nt][2], acc[mt][nt][3]);
      *(uint2*)(dst + (size_t)node * 64 + dw0 + mt * 8) = p;
    }
  }
}

// ---------------------------------------------------------------------------
// K3: exclusive scan of bucket counts -> bbase[nb+1], init gcur, sentinel
// ---------------------------------------------------------------------------
__global__ __launch_bounds__(256) void bscan(const int* __restrict__ bhist,
                                             int* __restrict__ bbase,
                                             int* __restrict__ gcur,
                                             int* __restrict__ offsets, int nb,
                                             int n, int e) {
  __shared__ int sd[256];
  int t = threadIdx.x;
  int v = (t < nb) ? bhist[t] : 0;
  sd[t] = v;
  __syncthreads();
#pragma unroll
  for (int s = 1; s < 256; s <<= 1) {
    int add = (t >= s) ? sd[t - s] : 0;
    __syncthreads();
    sd[t] += add;
    __syncthreads();
  }
  int excl = sd[t] - v;
  if (t < nb) {
    bbase[t] = excl;
    gcur[t] = excl;
  } else {
    gcur[t] = 0;
  }
  if (t == 0) {
    bbase[nb] = e;
    offsets[n] = e;
  }
}

// ---------------------------------------------------------------------------
// K4: partition. Single global read pass; entry src(16)|ldst(8)<<16|bkt(8)<<24
// cached in LDS; pass 2 zero global reads.
// ---------------------------------------------------------------------------
__global__ __launch_bounds__(256) void partition(const int* __restrict__ ei,
                                                 int* __restrict__ gcur,
                                                 unsigned int* __restrict__ ebuf,
                                                 int e) {
  __shared__ unsigned int ent[CHUNK];  // 8KB
  __shared__ int hist[256];
  __shared__ int lcur[256];
  const int t = threadIdx.x;
  const int c0 = blockIdx.x * CHUNK;
  const int cend = min(c0 + CHUNK, e);
  hist[t] = 0;
  __syncthreads();
  for (int i = c0 + t; i < cend; i += 256) {
    const int dst = ei[e + i];
    const int src = ei[i];
    const int b = dst >> NBSHIFT;
    atomicAdd(&hist[b], 1);
    ent[i - c0] = (unsigned int)src | ((unsigned int)(dst & 255) << 16) |
                  ((unsigned int)b << 24);
  }
  __syncthreads();
  lcur[t] = atomicAdd(&gcur[t], hist[t]);
  __syncthreads();
  for (int i = c0 + t; i < cend; i += 256) {
    const unsigned int u = ent[i - c0];
    const int b = u >> 24;
    int pos = atomicAdd(&lcur[b], 1);
    ebuf[pos] = u;
  }
}

// ---------------------------------------------------------------------------
// K5: per-bucket CSR build (1024 thr/block; csr_src is uint16).
// ---------------------------------------------------------------------------
__global__ __launch_bounds__(1024) void csr_build(
    const unsigned int* __restrict__ ebuf, const int* __restrict__ bbase,
    int* __restrict__ offsets, unsigned short* __restrict__ csr16, int n) {
  __shared__ int hist[256];
  __shared__ int sc[256];
  const int b = blockIdx.x;
  const int t = threadIdx.x;
  const int node0 = b << NBSHIFT;
  const int seg0 = bbase[b];
  const int seg1 = bbase[b + 1];

  if (t < 256) hist[t] = 0;
  __syncthreads();
  for (int i = seg0 + t; i < seg1; i += 1024)
    atomicAdd(&hist[(ebuf[i] >> 16) & 255], 1);
  __syncthreads();
  int v = 0;
  if (t < 256) {
    v = hist[t];
    sc[t] = v;
  }
  __syncthreads();
#pragma unroll
  for (int s = 1; s < 256; s <<= 1) {
    int add = (t >= s && t < 256) ? sc[t - s] : 0;
    __syncthreads();
    if (t < 256) sc[t] += add;
    __syncthreads();
  }
  if (t < 256) {
    int start = seg0 + sc[t] - v;
    int node = node0 + t;
    if (node < n) offsets[node] = start;
    hist[t] = start;
  }
  __syncthreads();
  for (int i = seg0 + t; i < seg1; i += 1024) {
    unsigned int u = ebuf[i];
    int pos = atomicAdd(&hist[(u >> 16) & 255], 1);
    csr16[pos] = (unsigned short)(u & 0xFFFFu);
  }
}

// ---------------------------------------------------------------------------
// K6: per-node softmax attention + aggregation.
// R17: explicit 16-edge batches — 4 shfl broadcasts + 4 INDEPENDENT uint4
// gathers into named registers BEFORE any consumption. R9-R16's
// `#pragma unroll 4` did NOT pipeline (VGPR=24 proves gathers were consumed
// serially); this enforces 4 loads in flight at source level (VGPR ~40+).
// ---------------------------------------------------------------------------
__global__ __launch_bounds__(256) void node_agg(
    const unsigned int* __restrict__ xlh, const unsigned int* __restrict__ xrh,
    const int* __restrict__ offsets, const unsigned short* __restrict__ csr16,
    const float* __restrict__ att, const float* __restrict__ bias,
    float* __restrict__ out, int n) {
  const int wave = threadIdx.x >> 6;
  const int lane = threadIdx.x & 63;
  const int node = blockIdx.x * 4 + wave;
  if (node >= n) return;
  const int q = lane >> 4;   // edge slot within quad
  const int r = lane & 15;   // channel group: ch 8r..8r+7 (head = r>>3)

  const uint4 xr4 = *(const uint4*)(xrh + (size_t)node * 64 + r * 4);
  const h2 xr0 = bch2(xr4.x), xr1 = bch2(xr4.y), xr2v = bch2(xr4.z),
           xr3 = bch2(xr4.w);
  const float4 a0 = *(const float4*)(att + r * 8);
  const float4 a1 = *(const float4*)(att + r * 8 + 4);
  const h2 ah0 = mkh2(a0.x, a0.y), ah1 = mkh2(a0.z, a0.w),
           ah2 = mkh2(a1.x, a1.y), ah3 = mkh2(a1.z, a1.w);

  const int start = rfl(offsets[node]);
  const int end = rfl(offsets[node + 1]);
  const int deg = end - start;
  const int T = deg + 1;  // +1 self-loop (slot 0)

  float s = 0.f;
  float accf[8];
#pragma unroll
  for (int i = 0; i < 8; ++i) accf[i] = 0.f;

  const char* __restrict__ xlbase = (const char*)xlh;
  const unsigned roff = (unsigned)(r * 16);

  auto gat = [&](int src) {
    return *(const uint4*)(xlbase + (((unsigned)src << 8) | roff));
  };

  auto quadp = [&](uint4 xl4, bool valid) {
    const h2 x0 = bch2(xl4.x), x1 = bch2(xl4.y), x2 = bch2(xl4.z),
             x3 = bch2(xl4.w);
    float p = 0.f;
    p = lkdot(x0, xr0, ah0, p);
    p = lkdot(x1, xr1, ah1, p);
    p = lkdot(x2, xr2v, ah2, p);
    p = lkdot(x3, xr3, ah3, p);
    // per-head reduce: 8 lanes per head within the 16-lane edge group
    p += swz<0x041F>(p);  // xor 1
    p += swz<0x081F>(p);  // xor 2
    p += swz<0x101F>(p);  // xor 4
    const float w = valid ? __expf(p) : 0.f;
    s += w;
    accf[0] = fmaf((float)x0.x, w, accf[0]);
    accf[1] = fmaf((float)x0.y, w, accf[1]);
    accf[2] = fmaf((float)x1.x, w, accf[2]);
    accf[3] = fmaf((float)x1.y, w, accf[3]);
    accf[4] = fmaf((float)x2.x, w, accf[4]);
    accf[5] = fmaf((float)x2.y, w, accf[5]);
    accf[6] = fmaf((float)x3.x, w, accf[6]);
    accf[7] = fmaf((float)x3.y, w, accf[7]);
  };

  for (int b0 = 0; b0 < T; b0 += 64) {
    const int m = min(64, T - b0);
    const int kk = b0 + lane;
    const int cl = min(kk, T - 1);
    int idx = node;
    if (deg > 0) {
      idx = csr16[start + max(cl - 1, 0)];
      if (cl == 0) idx = node;
    }
    int j = 0;
    // 16-edge batches: 4 independent gathers in flight before consumption
    for (; j + 16 <= m; j += 16) {
      const int s0 = __shfl(idx, j + q, 64);
      const int s1 = __shfl(idx, j + 4 + q, 64);
      const int s2 = __shfl(idx, j + 8 + q, 64);
      const int s3 = __shfl(idx, j + 12 + q, 64);
      const uint4 g0 = gat(s0);
      const uint4 g1 = gat(s1);
      const uint4 g2 = gat(s2);
      const uint4 g3 = gat(s3);
      quadp(g0, true);
      quadp(g1, true);
      quadp(g2, true);
      quadp(g3, true);
    }
    for (; j + 4 <= m; j += 4)
      quadp(gat(__shfl(idx, j + q, 64)), true);
    if (j < m) {
      const int eo = j + q;
      quadp(gat(__shfl(idx, min(eo, m - 1), 64)), eo < m);
    }
  }

  // cross-group (quad-slot) reduction: lanes 16 apart hold same channels/head
  s += swz<0x401F>(s);  // xor 16
  s += __shfl_xor(s, 32, 64);
#pragma unroll
  for (int i = 0; i < 8; ++i) {
    accf[i] += swz<0x401F>(accf[i]);
    accf[i] += __shfl_xor(accf[i], 32, 64);
  }

  if (q == 0) {
    const float inv = 1.f / s;  // per-head denominator (lane's head)
    const float4 b0v = *(const float4*)(bias + r * 8);
    const float4 b1v = *(const float4*)(bias + r * 8 + 4);
    float4 o0 = make_float4(fmaf(accf[0], inv, b0v.x), fmaf(accf[1], inv, b0v.y),
                            fmaf(accf[2], inv, b0v.z), fmaf(accf[3], inv, b0v.w));
    float4 o1 = make_float4(fmaf(accf[4], inv, b1v.x), fmaf(accf[5], inv, b1v.y),
                            fmaf(accf[6], inv, b1v.z), fmaf(accf[7], inv, b1v.w));
    *(float4*)(out + (size_t)node * 128 + r * 8) = o0;
    *(float4*)(out + (size_t)node * 128 + r * 8 + 4) = o1;
  }
}

// ---------------------------------------------------------------------------
// K7a: per-channel sum & sumsq partials (float4 loads, 512 blocks).
// ---------------------------------------------------------------------------
__global__ __launch_bounds__(256) void gn_partial(const float4* __restrict__ out4,
                                                  float* __restrict__ part,
                                                  int total4) {
  const int t = threadIdx.x;
  float s0 = 0.f, s1 = 0.f, s2 = 0.f, s3 = 0.f;
  float q0 = 0.f, q1 = 0.f, q2 = 0.f, q3 = 0.f;
  const int stride = gridDim.x * 256;
  for (int i = blockIdx.x * 256 + t; i < total4; i += stride) {
    float4 v = out4[i];
    s0 += v.x; q0 = fmaf(v.x, v.x, q0);
    s1 += v.y; q1 = fmaf(v.y, v.y, q1);
    s2 += v.z; q2 = fmaf(v.z, v.z, q2);
    s3 += v.w; q3 = fmaf(v.w, v.w, q3);
  }
  __shared__ float red[8][128];
  const int row = t >> 5;
  const int cb = (t & 31) * 4;
  *(float4*)&red[row][cb] = make_float4(s0, s1, s2, s3);
  __syncthreads();
  if (t < 128) {
    float S = 0.f;
#pragma unroll
    for (int r = 0; r < 8; ++r) S += red[r][t];
    part[blockIdx.x * 256 + t] = S;
  }
  __syncthreads();
  *(float4*)&red[row][cb] = make_float4(q0, q1, q2, q3);
  __syncthreads();
  if (t < 128) {
    float Q = 0.f;
#pragma unroll
    for (int r = 0; r < 8; ++r) Q += red[r][t];
    part[blockIdx.x * 256 + 128 + t] = Q;
  }
}

// K7b: combine partials (1024 thr = 128 ch x 8 slices, LDS fold)
__global__ __launch_bounds__(1024) void gn_final(const float* __restrict__ part,
                                                 const float* __restrict__ gw,
                                                 const float* __restrict__ gb,
                                                 const float* __restrict__ gms,
                                                 float* __restrict__ AB,
                                                 int nblocks, float inv_n) {
  __shared__ float sS[8][128];
  __shared__ float sQ[8][128];
  const int c = threadIdx.x & 127;
  const int sl = threadIdx.x >> 7;  // 0..7
  float S = 0.f, Q = 0.f;
#pragma unroll 8
  for (int b = sl; b < nblocks; b += 8) {
    S += part[b * 256 + c];
    Q += part[b * 256 + 128 + c];
  }
  sS[sl][c] = S;
  sQ[sl][c] = Q;
  __syncthreads();
  if (sl == 0) {
#pragma unroll
    for (int i = 1; i < 8; ++i) {
      S += sS[i][c];
      Q += sQ[i][c];
    }
    float mean = S * inv_n;
    float msc = mean * gms[c];
    float var = Q * inv_n - 2.f * msc * mean + msc * msc;
    float scale = gw[c] * rsqrtf(var + GN_EPS);
    AB[c] = scale;
    AB[128 + c] = gb[c] - scale * msc;
  }
}

// K7c: in-place normalize, float4-vectorized
__global__ void gn_apply(float* __restrict__ out, const float* __restrict__ AB,
                         int total4) {
  int i = blockIdx.x * blockDim.x + threadIdx.x;
  if (i >= total4) return;
  float4 v = ((float4*)out)[i];
  int c4 = (i & 31) * 4;
  v.x = fmaf(AB[c4 + 0], v.x, AB[128 + c4 + 0]);
  v.y = fmaf(AB[c4 + 1], v.y, AB[128 + c4 + 1]);
  v.z = fmaf(AB[c4 + 2], v.z, AB[128 + c4 + 2]);
  v.w = fmaf(AB[c4 + 3], v.w, AB[128 + c4 + 3]);
  ((float4*)out)[i] = v;
}

// ---------------------------------------------------------------------------
extern "C" void kernel_launch(void* const* d_in, const int* in_sizes, int n_in,
                              void* d_out, int out_size, void* d_ws,
                              size_t ws_size, hipStream_t stream) {
  const float* x = (const float*)d_in[0];
  const int* ei = (const int*)d_in[1];
  const float* Wl = (const float*)d_in[2];
  const float* Wr = (const float*)d_in[3];
  const float* att = (const float*)d_in[4];
  const float* bias = (const float*)d_in[5];
  const float* gw = (const float*)d_in[6];
  const float* gb = (const float*)d_in[7];
  const float* gms = (const float*)d_in[8];
  float* out = (float*)d_out;

  const int n = in_sizes[0] / 128;
  const int e = in_sizes[1] / 2;
  const int nb = (n + 255) >> NBSHIFT;       // coarse buckets (196)
  const int nchunks = (e + CHUNK - 1) / CHUNK;
  const int GN_BLOCKS = 512;
  const int gemm_blocks = (n + 63) / 64;
  const int hist_blocks = 196;

  char* w = (char*)d_ws;
  auto alloc = [&](size_t bytes) {
    char* p = w;
    w += (bytes + 255) & ~(size_t)255;
    return p;
  };
  unsigned int* xlb = (unsigned int*)alloc((size_t)n * 64 * sizeof(int));
  unsigned int* xrh = (unsigned int*)alloc((size_t)n * 64 * sizeof(int));
  int* offsets = (int*)alloc((size_t)(n + 1) * sizeof(int));
  unsigned short* csr16 =
      (unsigned short*)alloc((size_t)e * sizeof(unsigned short));
  unsigned int* ebuf = (unsigned int*)alloc((size_t)e * sizeof(int));
  int* bhist = (int*)alloc(256 * sizeof(int));
  int* bbase = (int*)alloc((size_t)(nb + 1) * sizeof(int));
  int* gcur = (int*)alloc(256 * sizeof(int));
  float* part = (float*)alloc((size_t)GN_BLOCKS * 256 * sizeof(float));
  float* AB = (float*)alloc(256 * sizeof(float));

  hipMemsetAsync(bhist, 0, 256 * sizeof(int), stream);

  gemm_hist<<<gemm_blocks + hist_blocks, 256, 0, stream>>>(
      x, Wl, Wr, xlb, xrh, n, ei, bhist, e, gemm_blocks);
  bscan<<<1, 256, 0, stream>>>(bhist, bbase, gcur, offsets, nb, n, e);
  partition<<<nchunks, 256, 0, stream>>>(ei, gcur, ebuf, e);
  csr_build<<<nb, 1024, 0, stream>>>(ebuf, bbase, offsets, csr16, n);
  node_agg<<<(n + 3) / 4, 256, 0, stream>>>(xlb, xrh, offsets, csr16, att,
                                            bias, out, n);
  gn_partial<<<GN_BLOCKS, 256, 0, stream>>>((const float4*)out, part, n * 32);
  gn_final<<<1, 1024, 0, stream>>>(part, gw, gb, gms, AB, GN_BLOCKS,
                                   1.0f / (float)n);
  gn_apply<<<(n * 32 + 255) / 256, 256, 0, stream>>>(out, AB, n * 32);
}